// Round 21
// baseline (70.148 us; speedup 1.0000x reference)
//
#include <hip/hip_runtime.h>
#include <hip/hip_bf16.h>

// Problem constants (from reference)
#define NB 4       // batch
#define CIN 32
#define TT 8       // time steps
#define NN 2000    // nodes
#define NE 16000   // edges
#define H1C 128
#define H2C 256
#define COUT 64
#define BT (NB*TT) // 32 graph replicas
#define BNN 2048   // padded node count
#define CMPSZ 22016 // >= NE + 3*NN (quad-padded rows)
#define WINV (1.0f/65535.0f)

// =============== kernel 1: fully self-contained S^3*X ===============
// grid (8, 32) = 256 blocks (1/CU), 1024 threads.
// Per block: exact CSR in LDS (int4-vectorized count -> scan(+quad-pad) -> fill
// -> zero-pad), degree-sorted node->lane assignment (counting sort), planar
// feature storage Yp[4][BNN] (b32 reads, ~conflict-free), 3 branch-light
// propagation passes, coalesced store.
// bt==1 blocks also fold weights (8-col slice); block (0,0) also emits r1/r2.
__global__ __launch_bounds__(1024) void k_sss(
    const float* __restrict__ x,
    const int* __restrict__ src, const int* __restrict__ dst,
    const float* __restrict__ ew,
    const float* __restrict__ W1, const float* __restrict__ b1,
    const float* __restrict__ W2, const float* __restrict__ b2,
    const float* __restrict__ W3,
    float* __restrict__ r1f, float* __restrict__ r2f,
    float* __restrict__ W123_g, float* __restrict__ d1_g, float* __restrict__ d2_g,
    float* __restrict__ C3)     // [bt][32][2000] channel-major
{
    __shared__ unsigned int cmp[CMPSZ];    // 88064 B packed edges (src<<16|w16), quad-padded CSR
    __shared__ float Yp[4 * BNN];          // 32768 B planar features: Yp[c*BNN + n]
    __shared__ float idg[BNN];             // 8192 B 1/deg
    __shared__ unsigned short rp[BNN + 2]; // 4100 B rowptr (max 22000 < 65536)
    __shared__ int cc_[BNN];               // 8192 B count/cursor, later ord[]
    __shared__ int ssc[256];               // 1024 B scan temp + sort hist/cursors

    const int tid = threadIdx.x;
    const int cg = blockIdx.x, bt = blockIdx.y;
    const int b = bt >> 3, t = bt & 7;

    // ---- weight folding (bt==1 blocks), cmp region as scratch ----
    if (bt == 1) {
        float* W3s  = (float*)cmp;            // 2048 floats
        float* W23s = (float*)cmp + H2C * 8;  // 1032 floats
        const int j0 = cg * 8;

        for (int i = tid; i < H2C * 8; i += 1024)
            W3s[i] = W3[(size_t)(i >> 3) * COUT + j0 + (i & 7)];
        __syncthreads();

        for (int r = tid >> 3; r < H1C + 1; r += 128) {
            int j = tid & 7;
            const float* wrow = (r < H1C) ? (W2 + (size_t)r * H2C) : b2;
            float a0 = 0, a1 = 0, a2 = 0, a3 = 0;
            for (int k = 0; k < H2C; k += 4) {
                float4 wv = *(const float4*)(wrow + k);
                a0 += wv.x * W3s[(k + 0) * 8 + j];
                a1 += wv.y * W3s[(k + 1) * 8 + j];
                a2 += wv.z * W3s[(k + 2) * 8 + j];
                a3 += wv.w * W3s[(k + 3) * 8 + j];
            }
            W23s[r * 8 + j] = (a0 + a1) + (a2 + a3);
        }
        __syncthreads();

        for (int r = tid >> 3; r < CIN + 1; r += 128) {
            int j = tid & 7;
            const float* wrow = (r < CIN) ? (W1 + (size_t)r * H1C) : b1;
            float a0 = 0, a1 = 0, a2 = 0, a3 = 0;
            for (int k = 0; k < H1C; k += 4) {
                float4 wv = *(const float4*)(wrow + k);
                a0 += wv.x * W23s[(k + 0) * 8 + j];
                a1 += wv.y * W23s[(k + 1) * 8 + j];
                a2 += wv.z * W23s[(k + 2) * 8 + j];
                a3 += wv.w * W23s[(k + 3) * 8 + j];
            }
            float acc = (a0 + a1) + (a2 + a3);
            if (r < CIN) W123_g[(size_t)r * COUT + j0 + j] = acc;
            else         d1_g[j0 + j] = acc;
        }
        if (tid < 8) d2_g[j0 + tid] = W23s[H1C * 8 + tid];
        __syncthreads();   // cmp free again
    }

    // ---- count (int4-vectorized) ----
    for (int i = tid; i < BNN; i += 1024) cc_[i] = 0;
    __syncthreads();
    const int4*   dst4 = (const int4*)dst;
    const int4*   src4 = (const int4*)src;
    const float4* ew4  = (const float4*)ew;
    #pragma unroll
    for (int i = 0; i < 4; i++) {
        int j = tid + i * 1024;
        if (j < NE / 4) {
            int4 d4 = dst4[j];
            atomicAdd(&cc_[d4.x], 1);
            atomicAdd(&cc_[d4.y], 1);
            atomicAdd(&cc_[d4.z], 1);
            atomicAdd(&cc_[d4.w], 1);
        }
    }
    __syncthreads();

    // ---- scan of quad-padded counts -> rp; cc_ becomes fill cursor (=rp) ----
    int local[8];
    if (tid < 256) {
        int base = tid * 8, sum = 0;
        #pragma unroll
        for (int i = 0; i < 8; i++) {
            int cnp = (cc_[base + i] + 3) & ~3;
            local[i] = sum;
            sum += cnp;
        }
        ssc[tid] = sum;
    }
    __syncthreads();
    for (int off = 1; off < 256; off <<= 1) {
        int v = 0;
        if (tid < 256 && tid >= off) v = ssc[tid - off];
        __syncthreads();
        if (tid < 256 && tid >= off) ssc[tid] += v;
        __syncthreads();
    }
    if (tid < 256) {
        int ce = (tid > 0) ? ssc[tid - 1] : 0;
        int base = tid * 8;
        #pragma unroll
        for (int i = 0; i < 8; i++) {
            int v = ce + local[i];
            rp[base + i] = (unsigned short)v;
            cc_[base + i] = v;
        }
        if (tid == 255) rp[BNN] = (unsigned short)ssc[255];
    }
    __syncthreads();

    // ---- fill (vectorized loads, LDS atomic slot claim) ----
    #pragma unroll
    for (int i = 0; i < 4; i++) {
        int j = tid + i * 1024;
        if (j < NE / 4) {
            int4 s4 = src4[j]; int4 d4 = dst4[j]; float4 w4 = ew4[j];
            unsigned int w; int pos;
            w = __float2uint_rn(w4.x * 65535.0f); if (w > 65535u) w = 65535u;
            pos = atomicAdd(&cc_[d4.x], 1); cmp[pos] = ((unsigned)s4.x << 16) | w;
            w = __float2uint_rn(w4.y * 65535.0f); if (w > 65535u) w = 65535u;
            pos = atomicAdd(&cc_[d4.y], 1); cmp[pos] = ((unsigned)s4.y << 16) | w;
            w = __float2uint_rn(w4.z * 65535.0f); if (w > 65535u) w = 65535u;
            pos = atomicAdd(&cc_[d4.z], 1); cmp[pos] = ((unsigned)s4.z << 16) | w;
            w = __float2uint_rn(w4.w * 65535.0f); if (w > 65535u) w = 65535u;
            pos = atomicAdd(&cc_[d4.w], 1); cmp[pos] = ((unsigned)s4.w << 16) | w;
        }
    }
    __syncthreads();

    // ---- deg + zero-pad rows to quad boundary ----
    #pragma unroll
    for (int h = 0; h < 2; h++) {
        int n = tid + h * 1024;
        int p0 = rp[n], p1 = cc_[n], pe = rp[n + 1];
        float s = 0.f;
        for (int p = p0; p < p1; p++) s += (float)(cmp[p] & 0xffffu);
        for (int p = p1; p < pe; p++) cmp[p] = 0u;
        idg[n] = 1.0f / (1.0f + s * WINV);
    }
    __syncthreads();

    // ---- counting sort by row length -> ord in cc_ ----
    if (tid < 128) ssc[tid] = 0;
    __syncthreads();
    #pragma unroll
    for (int h = 0; h < 2; h++) {
        int n = tid + h * 1024;
        int bin = min((int)(rp[n + 1] - rp[n]) >> 2, 63);
        atomicAdd(&ssc[bin], 1);
    }
    __syncthreads();
    if (tid < 64) {
        int v = ssc[tid], s = v;
        #pragma unroll
        for (int off = 1; off < 64; off <<= 1) {
            int u = __shfl_up(s, off);
            if (tid >= off) s += u;
        }
        ssc[64 + tid] = s - v;   // exclusive
    }
    __syncthreads();
    #pragma unroll
    for (int h = 0; h < 2; h++) {
        int n = tid + h * 1024;
        int bin = min((int)(rp[n + 1] - rp[n]) >> 2, 63);
        int pos = atomicAdd(&ssc[64 + bin], 1);
        cc_[pos] = n;            // ord
    }
    __syncthreads();

    // ---- block (0,0): r1 = S*1, r2 = S*r1 (Yp as scalar scratch) ----
    if (cg == 0 && bt == 0) {
        for (int n = tid; n < BNN; n += 1024) Yp[n] = sqrtf(idg[n]);
        __syncthreads();
        for (int n = tid; n < NN; n += 1024) {
            float s = 0.f;
            for (int p = rp[n]; p < rp[n + 1]; p++) {
                unsigned g = cmp[p];
                s += (float)(g & 0xffffu) * Yp[g >> 16];
            }
            float r = Yp[n] * (Yp[n] + s * WINV);
            r1f[n] = r;
            Yp[BNN + n] = Yp[n] * r;
        }
        __syncthreads();
        for (int n = tid; n < NN; n += 1024) {
            float s = 0.f;
            for (int p = rp[n]; p < rp[n + 1]; p++) {
                unsigned g = cmp[p];
                s += (float)(g & 0xffffu) * Yp[BNN + (g >> 16)];
            }
            r2f[n] = Yp[n] * (Yp[BNN + n] + s * WINV);
        }
        __syncthreads();
    }

    // ---- stage W0 = x * sqrt(idg), planar ----
    for (int n = tid; n < BNN; n += 1024) {
        if (n < NN) {
            float sq = sqrtf(idg[n]);
            Yp[0 * BNN + n] = x[(((size_t)b * CIN + cg * 4 + 0) * TT + t) * NN + n] * sq;
            Yp[1 * BNN + n] = x[(((size_t)b * CIN + cg * 4 + 1) * TT + t) * NN + n] * sq;
            Yp[2 * BNN + n] = x[(((size_t)b * CIN + cg * 4 + 2) * TT + t) * NN + n] * sq;
            Yp[3 * BNN + n] = x[(((size_t)b * CIN + cg * 4 + 3) * TT + t) * NN + n] * sq;
        } else {
            Yp[0 * BNN + n] = 0.f; Yp[1 * BNN + n] = 0.f;
            Yp[2 * BNN + n] = 0.f; Yp[3 * BNN + n] = 0.f;
        }
    }
    __syncthreads();

    // ---- three propagation passes: sorted nodes, quad-unrolled, planar reads ----
    const int na = cc_[2 * tid], nb = cc_[2 * tid + 1];
    const int ra = rp[na]; const int ca = (int)rp[na + 1] - ra;
    const int rb = rp[nb]; const int cb = (int)rp[nb + 1] - rb;
    const int mx = max(ca, cb);

    for (int pass = 0; pass < 3; pass++) {
        float a0 = Yp[0 * BNN + na], a1 = Yp[1 * BNN + na];
        float a2 = Yp[2 * BNN + na], a3 = Yp[3 * BNN + na];
        float c0 = Yp[0 * BNN + nb], c1 = Yp[1 * BNN + nb];
        float c2 = Yp[2 * BNN + nb], c3 = Yp[3 * BNN + nb];
        for (int k = 0; k < mx; k += 4) {
            if (k < ca) {
                uint4 e = *(const uint4*)&cmp[ra + k];
                {
                    float w = (float)(e.x & 0xffffu) * WINV; int s = e.x >> 16;
                    a0 += w * Yp[s]; a1 += w * Yp[BNN + s];
                    a2 += w * Yp[2 * BNN + s]; a3 += w * Yp[3 * BNN + s];
                }
                {
                    float w = (float)(e.y & 0xffffu) * WINV; int s = e.y >> 16;
                    a0 += w * Yp[s]; a1 += w * Yp[BNN + s];
                    a2 += w * Yp[2 * BNN + s]; a3 += w * Yp[3 * BNN + s];
                }
                {
                    float w = (float)(e.z & 0xffffu) * WINV; int s = e.z >> 16;
                    a0 += w * Yp[s]; a1 += w * Yp[BNN + s];
                    a2 += w * Yp[2 * BNN + s]; a3 += w * Yp[3 * BNN + s];
                }
                {
                    float w = (float)(e.w & 0xffffu) * WINV; int s = e.w >> 16;
                    a0 += w * Yp[s]; a1 += w * Yp[BNN + s];
                    a2 += w * Yp[2 * BNN + s]; a3 += w * Yp[3 * BNN + s];
                }
            }
            if (k < cb) {
                uint4 e = *(const uint4*)&cmp[rb + k];
                {
                    float w = (float)(e.x & 0xffffu) * WINV; int s = e.x >> 16;
                    c0 += w * Yp[s]; c1 += w * Yp[BNN + s];
                    c2 += w * Yp[2 * BNN + s]; c3 += w * Yp[3 * BNN + s];
                }
                {
                    float w = (float)(e.y & 0xffffu) * WINV; int s = e.y >> 16;
                    c0 += w * Yp[s]; c1 += w * Yp[BNN + s];
                    c2 += w * Yp[2 * BNN + s]; c3 += w * Yp[3 * BNN + s];
                }
                {
                    float w = (float)(e.z & 0xffffu) * WINV; int s = e.z >> 16;
                    c0 += w * Yp[s]; c1 += w * Yp[BNN + s];
                    c2 += w * Yp[2 * BNN + s]; c3 += w * Yp[3 * BNN + s];
                }
                {
                    float w = (float)(e.w & 0xffffu) * WINV; int s = e.w >> 16;
                    c0 += w * Yp[s]; c1 += w * Yp[BNN + s];
                    c2 += w * Yp[2 * BNN + s]; c3 += w * Yp[3 * BNN + s];
                }
            }
        }
        __syncthreads();   // all reads of Yp complete
        float sa = (pass < 2) ? idg[na] : sqrtf(idg[na]);
        float sb = (pass < 2) ? idg[nb] : sqrtf(idg[nb]);
        Yp[0 * BNN + na] = a0 * sa; Yp[1 * BNN + na] = a1 * sa;
        Yp[2 * BNN + na] = a2 * sa; Yp[3 * BNN + na] = a3 * sa;
        Yp[0 * BNN + nb] = c0 * sb; Yp[1 * BNN + nb] = c1 * sb;
        Yp[2 * BNN + nb] = c2 * sb; Yp[3 * BNN + nb] = c3 * sb;
        __syncthreads();
    }

    // ---- coalesced store ----
    float* base = C3 + ((size_t)bt * CIN + cg * 4) * NN;
    for (int n = tid; n < NN; n += 1024) {
        base[0 * NN + n] = Yp[0 * BNN + n];
        base[1 * NN + n] = Yp[1 * BNN + n];
        base[2 * NN + n] = Yp[2 * BNN + n];
        base[3 * NN + n] = Yp[3 * BNN + n];
    }
}

// =============== kernel 2: P = C3@W123 + r2*d1 + r1*d2 + b3; out = relu(P), transposed ===============
__global__ __launch_bounds__(256) void k_out(
    const float* __restrict__ C3,       // [bt][32][2000]
    const float* __restrict__ W123,     // 32x64
    const float* __restrict__ d1, const float* __restrict__ d2,
    const float* __restrict__ b3,
    const float* __restrict__ r1f, const float* __restrict__ r2f,
    float* __restrict__ out)            // [B][COUT][T][N]
{
    __shared__ float Cs[CIN][65];
    __shared__ float Ws[CIN][64];
    __shared__ float Os[64][65];
    __shared__ float d1s[64], d2s[64], b3s[64], r1s[64], r2s[64];
    const int tid = threadIdx.x;
    const int bt = blockIdx.y, b = bt >> 3, t = bt & 7;
    const int n0 = blockIdx.x * 64;

    for (int i = tid; i < CIN * 64; i += 256) {
        int ch = i >> 6, nn = i & 63;
        int n = n0 + nn;
        Cs[ch][nn] = (n < NN) ? C3[((size_t)bt * CIN + ch) * NN + n] : 0.f;
    }
    for (int i = tid; i < CIN * 64; i += 256)
        Ws[i >> 6][i & 63] = W123[i];
    if (tid < 64) {
        d1s[tid] = d1[tid];
        d2s[tid] = d2[tid];
        b3s[tid] = b3[tid];
        int n = n0 + tid;
        r1s[tid] = (n < NN) ? r1f[n] : 0.f;
        r2s[tid] = (n < NN) ? r2f[n] : 0.f;
    }
    __syncthreads();

    const int c = tid & 63, g = tid >> 6;
    for (int i = 0; i < 16; i++) {
        int nn = g * 16 + i;
        float acc = r2s[nn] * d1s[c] + r1s[nn] * d2s[c] + b3s[c];
        #pragma unroll
        for (int k = 0; k < CIN; k++) acc += Cs[k][nn] * Ws[k][c];
        Os[nn][c] = fmaxf(acc, 0.f);
    }
    __syncthreads();

    #pragma unroll
    for (int pass = 0; pass < 16; pass++) {
        int cc = g + pass * 4;
        int n = n0 + (tid & 63);
        if (n < NN)
            out[(((size_t)b * COUT + cc) * TT + t) * NN + n] = Os[tid & 63][cc];
    }
}

// ---------------- launch: exactly TWO dispatches ----------------

extern "C" void kernel_launch(void* const* d_in, const int* in_sizes, int n_in,
                              void* d_out, int out_size, void* d_ws, size_t ws_size,
                              hipStream_t stream) {
    (void)in_sizes; (void)n_in; (void)out_size; (void)ws_size;

    const float* x  = (const float*)d_in[0];
    const int*   ei = (const int*)d_in[1];
    const float* ew = (const float*)d_in[2];
    const float* W1 = (const float*)d_in[3];
    const float* b1 = (const float*)d_in[4];
    const float* W2 = (const float*)d_in[5];
    const float* b2 = (const float*)d_in[6];
    const float* W3 = (const float*)d_in[7];
    const float* b3 = (const float*)d_in[8];
    float* out = (float*)d_out;

    const int* src = ei;
    const int* dst = ei + NE;

    // workspace layout (float units) — all pure overwrites, replay-safe
    float* wsf  = (float*)d_ws;
    float* r1f  = wsf;            // 2048
    float* r2f  = wsf + 2048;     // 2048
    float* W123 = wsf + 4096;     // 2048
    float* d1   = wsf + 6144;     // 64
    float* d2   = wsf + 6208;     // 64
    float* C3   = wsf + 6272;     // 32*32*2000 floats

    k_sss<<<dim3(8, BT), dim3(1024), 0, stream>>>(
        x, src, dst, ew, W1, b1, W2, b2, W3,
        r1f, r2f, W123, d1, d2, C3);

    k_out<<<dim3(32, BT), dim3(256), 0, stream>>>(
        C3, W123, d1, d2, b3, r1f, r2f, out);
}